// Round 1
// baseline (480.586 us; speedup 1.0000x reference)
//
#include <hip/hip_runtime.h>

#define HIDDEN 64

// ---------- degrees via global int atomics (random over N -> low contention) ----------
__global__ __launch_bounds__(256) void degree_kernel(const int* __restrict__ src,
                                                     const int* __restrict__ dst,
                                                     int* __restrict__ outdeg,
                                                     int* __restrict__ indeg,
                                                     int E) {
    int E4 = E >> 2;
    int i = blockIdx.x * 256 + threadIdx.x;
    int stride = gridDim.x * 256;
    const int4* s4 = (const int4*)src;
    const int4* d4 = (const int4*)dst;
    for (; i < E4; i += stride) {
        int4 s = s4[i];
        int4 d = d4[i];
        atomicAdd(&outdeg[s.x], 1);
        atomicAdd(&outdeg[s.y], 1);
        atomicAdd(&outdeg[s.z], 1);
        atomicAdd(&outdeg[s.w], 1);
        atomicAdd(&indeg[d.x], 1);
        atomicAdd(&indeg[d.y], 1);
        atomicAdd(&indeg[d.z], 1);
        atomicAdd(&indeg[d.w], 1);
    }
    int rem = E - (E4 << 2);
    if (blockIdx.x == 0 && threadIdx.x < rem) {
        int e = (E4 << 2) + threadIdx.x;
        atomicAdd(&outdeg[src[e]], 1);
        atomicAdd(&indeg[dst[e]], 1);
    }
}

// ---------- embu (+ fused weight-chain): embu[v] = emb[v] . u1 ----------
// Each block recomputes u3=W2@Wreg, u2=W1@u3, u1=W0@u2 in LDS (12K MACs).
// Block 0 also writes c1,c2,c3 to wt[64..66].
__global__ __launch_bounds__(256) void embu_kernel(const float* __restrict__ emb,
                                                   const float* __restrict__ Ws,
                                                   const float* __restrict__ bs,
                                                   const float* __restrict__ Wreg,
                                                   float* __restrict__ wt,
                                                   float* __restrict__ embu, int V) {
    __shared__ float u3[HIDDEN], u2[HIDDEN], u1[HIDDEN];
    int t = threadIdx.x;
    const float* W0 = Ws;
    const float* W1 = Ws + HIDDEN * HIDDEN;
    const float* W2 = Ws + 2 * HIDDEN * HIDDEN;
    if (t < HIDDEN) {
        float s = 0.0f;
        for (int j = 0; j < HIDDEN; j++) s += W2[t * HIDDEN + j] * Wreg[j];
        u3[t] = s;
    }
    __syncthreads();
    if (t < HIDDEN) {
        float s = 0.0f;
        for (int j = 0; j < HIDDEN; j++) s += W1[t * HIDDEN + j] * u3[j];
        u2[t] = s;
    }
    __syncthreads();
    if (t < HIDDEN) {
        float s = 0.0f;
        for (int j = 0; j < HIDDEN; j++) s += W0[t * HIDDEN + j] * u2[j];
        u1[t] = s;
    }
    __syncthreads();
    if (blockIdx.x == 0 && t < HIDDEN) {
        float c1v = bs[t] * u2[t];
        float c2v = bs[HIDDEN + t] * u3[t];
        float c3v = bs[2 * HIDDEN + t] * Wreg[t];
#pragma unroll
        for (int off = 32; off > 0; off >>= 1) {
            c1v += __shfl_down(c1v, off, 64);
            c2v += __shfl_down(c2v, off, 64);
            c3v += __shfl_down(c3v, off, 64);
        }
        if (t == 0) { wt[64] = c1v; wt[65] = c2v; wt[66] = c3v; }
    }
    int lane = t & 63;
    int warp = t >> 6;
    int vs = lane >> 4, ln = lane & 15;
    int v = blockIdx.x * 16 + warp * 4 + vs;
    if (v >= V) return;
    const float* row = emb + (size_t)v * HIDDEN;
    float acc = row[ln] * u1[ln] + row[16 + ln] * u1[16 + ln]
              + row[32 + ln] * u1[32 + ln] + row[48 + ln] * u1[48 + ln];
    acc += __shfl_xor(acc, 1, 64);
    acc += __shfl_xor(acc, 2, 64);
    acc += __shfl_xor(acc, 4, 64);
    acc += __shfl_xor(acc, 8, 64);
    if (ln == 0) embu[v] = acc;
}

// ---------- norms + y0 fused: ndst/nsrc from degrees, y0[n] = embu[feats[n]]*nsrc[n] ----------
__global__ __launch_bounds__(256) void norm_y0_kernel(const int* __restrict__ indeg,
                                                      const int* __restrict__ outdeg,
                                                      const int* __restrict__ feats,
                                                      const float* __restrict__ embu,
                                                      float* __restrict__ ndst,
                                                      float* __restrict__ nsrc,
                                                      float* __restrict__ y0, int N) {
    int n = blockIdx.x * 256 + threadIdx.x;
    if (n >= N) return;
    float nd = rsqrtf(fmaxf((float)indeg[n], 1.0f));
    float ns = rsqrtf(fmaxf((float)outdeg[n], 1.0f));
    ndst[n] = nd;
    nsrc[n] = ns;
    y0[n] = embu[feats[n]] * ns;
}

// ---------- edge-centric scalar SpMM: agg[dst] += y[src] via HW float atomics ----------
__global__ __launch_bounds__(256) void spmm_kernel(const int* __restrict__ src,
                                                   const int* __restrict__ dst,
                                                   const float* __restrict__ y,
                                                   float* __restrict__ agg,
                                                   int E) {
    int E4 = E >> 2;
    int i = blockIdx.x * 256 + threadIdx.x;
    int stride = gridDim.x * 256;
    const int4* s4 = (const int4*)src;
    const int4* d4 = (const int4*)dst;
    for (; i < E4; i += stride) {
        int4 s = s4[i];
        int4 d = d4[i];
        float vx = y[s.x];
        float vy = y[s.y];
        float vz = y[s.z];
        float vw = y[s.w];
        unsafeAtomicAdd(&agg[d.x], vx);
        unsafeAtomicAdd(&agg[d.y], vy);
        unsafeAtomicAdd(&agg[d.z], vz);
        unsafeAtomicAdd(&agg[d.w], vw);
    }
    int rem = E - (E4 << 2);
    if (blockIdx.x == 0 && threadIdx.x < rem) {
        int e = (E4 << 2) + threadIdx.x;
        unsafeAtomicAdd(&agg[dst[e]], y[src[e]]);
    }
}

// ---------- apply layer epilogue: y_out = (agg*ndst + c) * nsrc ----------
__global__ __launch_bounds__(256) void apply_kernel(const float* __restrict__ agg,
                                                    const float* __restrict__ ndst,
                                                    const float* __restrict__ nsrc,
                                                    const float* __restrict__ wt, int cidx,
                                                    float* __restrict__ yout, int N) {
    int n = blockIdx.x * 256 + threadIdx.x;
    if (n < N) yout[n] = (agg[n] * ndst[n] + wt[cidx]) * nsrc[n];
}

// ---------- last layer epilogue fused with pooling: nodeval = agg*ndst + c3,
// segmented wave-scan over sorted gids, one atomic per segment-tail ----------
__global__ __launch_bounds__(256) void apply_final_kernel(const float* __restrict__ agg,
                                                          const float* __restrict__ ndst,
                                                          const float* __restrict__ wt,
                                                          const int* __restrict__ gids,
                                                          float* __restrict__ out, int N) {
    int n = blockIdx.x * 256 + threadIdx.x;
    int lane = threadIdx.x & 63;
    float v = 0.0f;
    int g = -1;
    if (n < N) { v = agg[n] * ndst[n] + wt[66]; g = gids[n]; }
#pragma unroll
    for (int off = 1; off < 64; off <<= 1) {
        float u = __shfl_up(v, off, 64);
        int gu = __shfl_up(g, off, 64);
        if (lane >= off && gu == g) v += u;
    }
    int gn = __shfl_down(g, 1, 64);
    bool last = (lane == 63) || (gn != g);
    if (n < N && last) atomicAdd(&out[g], v);
}

extern "C" void kernel_launch(void* const* d_in, const int* in_sizes, int n_in,
                              void* d_out, int out_size, void* d_ws, size_t ws_size,
                              hipStream_t stream) {
    const int*   feats = (const int*)d_in[0];
    const int*   src   = (const int*)d_in[1];
    const int*   dst   = (const int*)d_in[2];
    const int*   gids  = (const int*)d_in[3];
    const float* emb   = (const float*)d_in[5];
    const float* Ws    = (const float*)d_in[6];
    const float* bs    = (const float*)d_in[7];
    const float* Wreg  = (const float*)d_in[8];
    float* out = (float*)d_out;

    int N = in_sizes[0];
    int E = in_sizes[1];
    int V = in_sizes[5] / HIDDEN;
    int NB = (N + 255) / 256;
    int E4 = E >> 2;
    int GE = (E4 + 255) / 256;              // ~1563 blocks for E=1.6M
    if (GE > 8192) GE = 8192;               // grid-stride beyond

    // workspace: [indeg N][outdeg N][agg1 N][agg2 N][agg3 N] (one contiguous memset)
    // then norms / y buffers / embu / wt
    char* p = (char*)d_ws;
    int*   indeg  = (int*)p;    p += (size_t)N * 4;
    int*   outdeg = (int*)p;    p += (size_t)N * 4;
    float* agg1   = (float*)p;  p += (size_t)N * 4;
    float* agg2   = (float*)p;  p += (size_t)N * 4;
    float* agg3   = (float*)p;  p += (size_t)N * 4;
    float* ndst   = (float*)p;  p += (size_t)N * 4;
    float* nsrc   = (float*)p;  p += (size_t)N * 4;
    float* y0     = (float*)p;  p += (size_t)N * 4;
    float* y1     = (float*)p;  p += (size_t)N * 4;
    float* y2     = (float*)p;  p += (size_t)N * 4;
    float* wt     = (float*)p;  p += 128 * 4;
    float* embu   = (float*)p;  p += (size_t)V * 4;

    hipMemsetAsync(out, 0, (size_t)out_size * 4, stream);
    hipMemsetAsync(indeg, 0, (size_t)5 * N * 4, stream);   // indeg/outdeg/agg1/agg2/agg3

    degree_kernel<<<GE, 256, 0, stream>>>(src, dst, outdeg, indeg, E);
    embu_kernel<<<(V + 15) / 16, 256, 0, stream>>>(emb, Ws, bs, Wreg, wt, embu, V);
    norm_y0_kernel<<<NB, 256, 0, stream>>>(indeg, outdeg, feats, embu, ndst, nsrc, y0, N);

    // layer 1..3: agg = A y;  y' = (agg*ndst + c)*nsrc  (last layer fused with pooling)
    spmm_kernel<<<GE, 256, 0, stream>>>(src, dst, y0, agg1, E);
    apply_kernel<<<NB, 256, 0, stream>>>(agg1, ndst, nsrc, wt, 64, y1, N);
    spmm_kernel<<<GE, 256, 0, stream>>>(src, dst, y1, agg2, E);
    apply_kernel<<<NB, 256, 0, stream>>>(agg2, ndst, nsrc, wt, 65, y2, N);
    spmm_kernel<<<GE, 256, 0, stream>>>(src, dst, y2, agg3, E);
    apply_final_kernel<<<NB, 256, 0, stream>>>(agg3, ndst, wt, gids, out, N);
}